// Round 14
// baseline (180.826 us; speedup 1.0000x reference)
//
#include <hip/hip_runtime.h>
#include <hip/hip_bf16.h>
#include <stdint.h>

#define B_ROWS 32768
#define DIM 512
#define THREADS 256
#define NKT 32              // K-steps of 32 over K=1024
#define ASLOT 8192          // 128 rows x 64 B (bf16), one A slot
#define LDS_TOTAL (2 * ASLOT)   // 16 KB

typedef __attribute__((ext_vector_type(8))) __bf16 bf16x8;
typedef __attribute__((ext_vector_type(4))) float f32x4;
typedef __attribute__((ext_vector_type(4))) unsigned int uint4v;

__device__ static inline unsigned short f2bf(float f) {
    unsigned int u = __builtin_bit_cast(unsigned int, f);
    u += 0x7fffu + ((u >> 16) & 1u);
    return (unsigned short)(u >> 16);
}

// Wt2[kt 0..31][t 0..2][n 0..511][64B], PLAIN layout: byte = kc*2 within row.
// Consumed by direct global->reg reads (1 KB contiguous per wave-instr).
__global__ void prep_weights(const float* __restrict__ Wu_x, const float* __restrict__ Wu_h,
                             const float* __restrict__ Wr_x, const float* __restrict__ Wr_h,
                             const float* __restrict__ Wc_x, const float* __restrict__ Wc_h,
                             unsigned short* __restrict__ Wt2) {
    __shared__ float tile[32][33];
    const int t = blockIdx.z;
    const int k0 = blockIdx.x * 32;
    const int n0 = blockIdx.y * 32;
    const float* Wx = (t == 0) ? Wu_x : (t == 1) ? Wr_x : Wc_x;
    const float* Wh = (t == 0) ? Wu_h : (t == 1) ? Wr_h : Wc_h;
    const int tid = threadIdx.x;
    const int c = tid & 31, r0 = tid >> 5;
#pragma unroll
    for (int i = 0; i < 4; ++i) {
        int kl = r0 + i * 8;
        int k = k0 + kl;
        int n = n0 + c;
        float v = (k < 512) ? Wx[(size_t)k * 512 + n] : Wh[(size_t)(k - 512) * 512 + n];
        tile[kl][c] = v;
    }
    __syncthreads();
    const int kt = k0 >> 5;
#pragma unroll
    for (int i = 0; i < 4; ++i) {
        int nl = r0 + i * 8;
        int kc = c;
        int n = n0 + nl;
        Wt2[(((size_t)kt * 3 + t) * 512 + n) * 32 + kc] = f2bf(tile[kc][nl]);
    }
}

// main: 256-thr, wave 64x32, block 128x64, BK=32.
// A: fp32 global->reg (asm, 1 body ahead) -> cvt_pk_bf16 -> LDS (2 slots, XOR swz).
// W: direct global->reg from L2-resident Wt2 (asm), bb ping-pong, 1 body ahead.
__global__ __launch_bounds__(THREADS, 2) void augru_main(
    const float* __restrict__ x, const float* __restrict__ h,
    const float* __restrict__ att, const unsigned short* __restrict__ Wt2,
    const float* __restrict__ bu, const float* __restrict__ br,
    const float* __restrict__ bc, float* __restrict__ out) {
    extern __shared__ char smem[];   // 16 KB
    const int tid = threadIdx.x;
    const int lane = tid & 63;
    const int wid = tid >> 6;   // 0..3
    const int wm = wid >> 1;    // 0..1 -> 64-row half
    const int wn = wid & 1;     // 0..1 -> 32-col half
    const int id = blockIdx.x;
    const int wg = (id & 7) * 256 + (id >> 3);   // XCD-bijective; siblings co-XCD
    const int nb = wg & 7;      // 0..7 -> 64-col block
    const int mb = wg >> 3;     // 0..255
    const int cl = lane & 15;
    const int kg = lane >> 4;

    f32x4 accU[4][2], accR[4][2], accCx[4][2], accCh[4][2];
#pragma unroll
    for (int i = 0; i < 4; ++i)
#pragma unroll
        for (int j = 0; j < 2; ++j) {
            accU[i][j] = (f32x4)(0.f);
            accR[i][j] = (f32x4)(0.f);
            accCx[i][j] = (f32x4)(0.f);
            accCh[i][j] = (f32x4)(0.f);
        }

    // A LDS read base (R11-verified swizzle; mi-invariant since 8*mi % 4 == 0)
    const int rowb = wm * 64 + cl;
    const int aBase = rowb * 64 + ((kg * 16) ^ (((rowb >> 1) & 3) << 4));

    // A conversion mapping: thread -> (row, 32B-half)   (R11-verified)
    const int arow = tid >> 1;            // 0..127
    const int ap = tid & 1;               // 0..1
    const int asw = ((arow >> 1) & 3) << 4;
    const int dsA0 = arow * 64 + ((ap * 32) ^ asw);
    const int dsA1 = arow * 64 + ((ap * 32 + 16) ^ asw);
    const float* pAx = x + (size_t)(mb * 128 + arow) * 512 + ap * 16;
    const float* pAh = h + (size_t)(mb * 128 + arow) * 512 - 512 + ap * 16;

    f32x4 fa[4];
    auto issueA = [&](int ktn) {
        const float* g = ((ktn < 16) ? pAx : pAh) + ktn * 32;
        asm volatile(
            "global_load_dwordx4 %0, %4, off\n\t"
            "global_load_dwordx4 %1, %4, off offset:16\n\t"
            "global_load_dwordx4 %2, %4, off offset:32\n\t"
            "global_load_dwordx4 %3, %4, off offset:48"
            : "=&v"(fa[0]), "=&v"(fa[1]), "=&v"(fa[2]), "=&v"(fa[3])
            : "v"(g)
            : "memory");
    };

    // W direct-to-reg: lane (cl,kg) reads col nb*64+wn*32+ni*16+cl, 16B at kg*16
    const char* gW = (const char*)Wt2
        + (size_t)((nb * 64 + wn * 32 + cl) * 64 + kg * 16);
    auto loadW = [&](bf16x8(&dst)[3][2], int ktn) {
        const char* p = gW + (size_t)ktn * 98304;
#pragma unroll
        for (int t = 0; t < 3; ++t) {
            asm volatile(
                "global_load_dwordx4 %0, %2, off\n\t"
                "global_load_dwordx4 %1, %2, off offset:1024"
                : "=&v"(dst[t][0]), "=&v"(dst[t][1])
                : "v"(p + t * 32768)
                : "memory");
        }
    };

    auto cvt2 = [](float lo, float hi) {
        unsigned int r;
        asm("v_cvt_pk_bf16_f32 %0, %1, %2" : "=v"(r) : "v"(lo), "v"(hi));
        return r;
    };
    auto convertA = [&](int slot) {   // fa landed (caller's vmcnt), -> slot
        uint4v q0, q1;
        q0.x = cvt2(fa[0][0], fa[0][1]); q0.y = cvt2(fa[0][2], fa[0][3]);
        q0.z = cvt2(fa[1][0], fa[1][1]); q0.w = cvt2(fa[1][2], fa[1][3]);
        q1.x = cvt2(fa[2][0], fa[2][1]); q1.y = cvt2(fa[2][2], fa[2][3]);
        q1.z = cvt2(fa[3][0], fa[3][1]); q1.w = cvt2(fa[3][2], fa[3][3]);
        char* base = smem + slot * ASLOT;
        *(uint4v*)(base + dsA0) = q0;
        *(uint4v*)(base + dsA1) = q1;
    };

    bf16x8 bbA[3][2], bbB[3][2];

    // prologue: A(0)->slot0; A(1)+W(0) in flight
    issueA(0);
    asm volatile("s_waitcnt vmcnt(0)" ::: "memory");
    __builtin_amdgcn_sched_barrier(0);
    convertA(0);
    issueA(1);
    loadW(bbA, 0);

    auto body = [&](int kt, bf16x8(&cur)[3][2], bf16x8(&nxt)[3][2],
                    f32x4(&accC)[4][2]) {
        asm volatile("s_waitcnt vmcnt(0) lgkmcnt(0)" ::: "memory"); // A(kt+1),W(kt) in
        __builtin_amdgcn_sched_barrier(0);   // rule 18: nothing hoists above the wait
        __builtin_amdgcn_s_barrier();        // slot writes visible; slot reuse safe
        if (kt + 1 < NKT) convertA((kt + 1) & 1);  // fa -> slot(kt+1); zero-wait
        if (kt + 2 < NKT) issueA(kt + 2);          // after cvt read of fa (WAR safe)
        if (kt + 1 < NKT) loadW(nxt, kt + 1);
        const char* aS = smem + (kt & 1) * ASLOT;
        bf16x8 a[4];
#pragma unroll
        for (int mi = 0; mi < 4; ++mi)
            a[mi] = __builtin_bit_cast(bf16x8,
                *(const uint4v*)(aS + aBase + mi * 1024));
        __builtin_amdgcn_s_setprio(1);
#pragma unroll
        for (int ni = 0; ni < 2; ++ni) {
#pragma unroll
            for (int mi = 0; mi < 4; ++mi)
                accU[mi][ni] = __builtin_amdgcn_mfma_f32_16x16x32_bf16(
                    a[mi], cur[0][ni], accU[mi][ni], 0, 0, 0);
#pragma unroll
            for (int mi = 0; mi < 4; ++mi)
                accR[mi][ni] = __builtin_amdgcn_mfma_f32_16x16x32_bf16(
                    a[mi], cur[1][ni], accR[mi][ni], 0, 0, 0);
#pragma unroll
            for (int mi = 0; mi < 4; ++mi)
                accC[mi][ni] = __builtin_amdgcn_mfma_f32_16x16x32_bf16(
                    a[mi], cur[2][ni], accC[mi][ni], 0, 0, 0);
        }
        __builtin_amdgcn_s_setprio(0);
    };

    body(0, bbA, bbB, accCx);  body(1, bbB, bbA, accCx);
    body(2, bbA, bbB, accCx);  body(3, bbB, bbA, accCx);
    body(4, bbA, bbB, accCx);  body(5, bbB, bbA, accCx);
    body(6, bbA, bbB, accCx);  body(7, bbB, bbA, accCx);
    body(8, bbA, bbB, accCx);  body(9, bbB, bbA, accCx);
    body(10, bbA, bbB, accCx); body(11, bbB, bbA, accCx);
    body(12, bbA, bbB, accCx); body(13, bbB, bbA, accCx);
    body(14, bbA, bbB, accCx); body(15, bbB, bbA, accCx);
    body(16, bbA, bbB, accCh); body(17, bbB, bbA, accCh);
    body(18, bbA, bbB, accCh); body(19, bbB, bbA, accCh);
    body(20, bbA, bbB, accCh); body(21, bbB, bbA, accCh);
    body(22, bbA, bbB, accCh); body(23, bbB, bbA, accCh);
    body(24, bbA, bbB, accCh); body(25, bbB, bbA, accCh);
    body(26, bbA, bbB, accCh); body(27, bbB, bbA, accCh);
    body(28, bbA, bbB, accCh); body(29, bbB, bbA, accCh);
    body(30, bbA, bbB, accCh); body(31, bbB, bbA, accCh);

    // ---- fused epilogue ----
#pragma unroll
    for (int ni = 0; ni < 2; ++ni) {
        const int col = nb * 64 + wn * 32 + ni * 16 + cl;
        const float bU = bu[col];
        const float bR = br[col];
        const float bC = bc[col];
#pragma unroll
        for (int mi = 0; mi < 4; ++mi) {
#pragma unroll
            for (int j = 0; j < 4; ++j) {
                const int row = mb * 128 + wm * 64 + mi * 16 + kg * 4 + j;
                const float up = accU[mi][ni][j] + bU;
                const float rp = accR[mi][ni][j] + bR;
                const float u = 1.f / (1.f + __expf(-up));
                const float r = 1.f / (1.f + __expf(-rp));
                const float cpre = accCx[mi][ni][j] + bC + r * accCh[mi][ni][j];
                const float e = __expf(-2.f * cpre);
                const float cc = (1.f - e) / (1.f + e);   // tanh
                const float aa = att[row];
                const float hv = h[(size_t)row * 512 + col];
                const float u_ = aa * u;
                out[(size_t)row * 512 + col] = (1.f - u_) * hv + u_ * cc;
            }
        }
    }
}

extern "C" void kernel_launch(void* const* d_in, const int* in_sizes, int n_in,
                              void* d_out, int out_size, void* d_ws, size_t ws_size,
                              hipStream_t stream) {
    const float* x    = (const float*)d_in[0];
    const float* h    = (const float*)d_in[1];
    const float* att  = (const float*)d_in[2];
    const float* Wu_x = (const float*)d_in[3];
    const float* bu   = (const float*)d_in[4];
    const float* Wu_h = (const float*)d_in[5];
    const float* Wr_x = (const float*)d_in[6];
    const float* br   = (const float*)d_in[7];
    const float* Wr_h = (const float*)d_in[8];
    const float* Wc_x = (const float*)d_in[9];
    const float* bc   = (const float*)d_in[10];
    const float* Wc_h = (const float*)d_in[11];
    unsigned short* Wt2 = (unsigned short*)d_ws;   // 3 MB
    float* out = (float*)d_out;

    prep_weights<<<dim3(32, 16, 3), 256, 0, stream>>>(Wu_x, Wu_h, Wr_x, Wr_h, Wc_x, Wc_h, Wt2);

    hipFuncSetAttribute((const void*)augru_main,
                        hipFuncAttributeMaxDynamicSharedMemorySize, LDS_TOTAL);
    augru_main<<<dim3(2048), THREADS, LDS_TOTAL, stream>>>(
        x, h, att, Wt2, bu, br, bc, out);
}

// Round 16
// 141.916 us; speedup vs baseline: 1.2742x; 1.2742x over previous
//
#include <hip/hip_runtime.h>
#include <hip/hip_bf16.h>
#include <stdint.h>

#define B_ROWS 32768
#define DIM 512
#define THREADS 256
#define NKT 32              // K-steps of 32 over K=1024
#define ASLOT 8192          // 128 rows x 64 B (bf16), one A slot
#define WBUFB 12288         // 3 mats x 64 cols x 64 B, one W buffer
#define WBASE 16384         // A slots occupy [0, 16384)
#define LDS_TOTAL (WBASE + 4 * WBUFB)   // 64 KB -> 2 blocks/CU

typedef __attribute__((ext_vector_type(8))) __bf16 bf16x8;
typedef __attribute__((ext_vector_type(4))) float f32x4;
typedef __attribute__((ext_vector_type(4))) unsigned int uint4v;

__device__ static inline unsigned short f2bf(float f) {
    unsigned int u = __builtin_bit_cast(unsigned int, f);
    u += 0x7fffu + ((u >> 16) & 1u);
    return (unsigned short)(u >> 16);
}

__device__ static inline void load_lds_16B(const void* g, void* lds) {
    __builtin_amdgcn_global_load_lds(
        (const __attribute__((address_space(1))) unsigned int*)g,
        (__attribute__((address_space(3))) unsigned int*)lds,
        16, 0, 0);
}

// Wt2[kt 0..31][t 0..2][n 0..511][64B]: element (t,n,k): kt=k>>5, kc=k&31,
// byte = (kc*2) ^ (((n>>1)&3)<<4).   (validated layout, 0-conflict)
__global__ void prep_weights(const float* __restrict__ Wu_x, const float* __restrict__ Wu_h,
                             const float* __restrict__ Wr_x, const float* __restrict__ Wr_h,
                             const float* __restrict__ Wc_x, const float* __restrict__ Wc_h,
                             unsigned short* __restrict__ Wt2) {
    __shared__ float tile[32][33];
    const int t = blockIdx.z;
    const int k0 = blockIdx.x * 32;
    const int n0 = blockIdx.y * 32;
    const float* Wx = (t == 0) ? Wu_x : (t == 1) ? Wr_x : Wc_x;
    const float* Wh = (t == 0) ? Wu_h : (t == 1) ? Wr_h : Wc_h;
    const int tid = threadIdx.x;
    const int c = tid & 31, r0 = tid >> 5;
#pragma unroll
    for (int i = 0; i < 4; ++i) {
        int kl = r0 + i * 8;
        int k = k0 + kl;
        int n = n0 + c;
        float v = (k < 512) ? Wx[(size_t)k * 512 + n] : Wh[(size_t)(k - 512) * 512 + n];
        tile[kl][c] = v;
    }
    __syncthreads();
    const int kt = k0 >> 5;
#pragma unroll
    for (int i = 0; i < 4; ++i) {
        int nl = r0 + i * 8;
        int kc = c;
        int n = n0 + nl;
        size_t base = (((size_t)kt * 3 + t) * 512 + n) * 64;
        *(unsigned short*)((char*)Wt2 + base + ((kc * 2) ^ (((n >> 1) & 3) << 4))) =
            f2bf(tile[kc][nl]);
    }
}

// main: 256-thr, wave 64x32, block 128x64, BK=32.
// A: fp32 global->reg issued 2 bodies ahead (ping-pong fa sets), converted
//    1 body ahead into 2 LDS slots. W: Wt2 global_load_lds, 4 bufs, 3 ahead.
__global__ __launch_bounds__(THREADS, 2) void augru_main(
    const float* __restrict__ x, const float* __restrict__ h,
    const float* __restrict__ att, const unsigned short* __restrict__ Wt2,
    const float* __restrict__ bu, const float* __restrict__ br,
    const float* __restrict__ bc, float* __restrict__ out) {
    extern __shared__ char smem[];   // 64 KB
    const int tid = threadIdx.x;
    const int lane = tid & 63;
    const int wid = tid >> 6;   // 0..3
    const int wm = wid >> 1;    // 0..1 -> 64-row half
    const int wn = wid & 1;     // 0..1 -> 32-col half
    const int id = blockIdx.x;
    const int wg = (id & 7) * 256 + (id >> 3);   // XCD-bijective; nb-siblings co-XCD
    const int nb = wg & 7;      // 0..7 -> 64-col block
    const int mb = wg >> 3;     // 0..255
    const int cl = lane & 15;
    const int kg = lane >> 4;

    f32x4 accU[4][2], accR[4][2], accCx[4][2], accCh[4][2];
#pragma unroll
    for (int i = 0; i < 4; ++i)
#pragma unroll
        for (int j = 0; j < 2; ++j) {
            accU[i][j] = (f32x4)(0.f);
            accR[i][j] = (f32x4)(0.f);
            accCx[i][j] = (f32x4)(0.f);
            accCh[i][j] = (f32x4)(0.f);
        }

    // LDS read bases; swizzle term is mi/ni-invariant (8*mi % 4 == 0)
    const int rowb = wm * 64 + cl;
    const int aBase = rowb * 64 + ((kg * 16) ^ (((rowb >> 1) & 3) << 4));
    const int colb = wn * 32 + cl;
    const int wBase = WBASE + colb * 64 + ((kg * 16) ^ (((colb >> 1) & 3) << 4));

    // A conversion mapping: thread -> (row, 32B-half)
    const int arow = tid >> 1;            // 0..127
    const int ap = tid & 1;               // 0..1
    const int asw = ((arow >> 1) & 3) << 4;
    const int dsA0 = arow * 64 + ((ap * 32) ^ asw);
    const int dsA1 = arow * 64 + ((ap * 32 + 16) ^ asw);
    const float* pAx = x + (size_t)(mb * 128 + arow) * 512 + ap * 16;
    const float* pAh = h + (size_t)(mb * 128 + arow) * 512 - 512 + ap * 16;

    // W staging (global_load_lds, 3 loads/thread)
    const char* gW0 = (const char*)Wt2 + ((size_t)nb * 64) * 64 + tid * 16;
    auto stageW = [&](int buf, int kt) {
        char* base = smem + WBASE + buf * WBUFB;
        const char* gW = gW0 + (size_t)kt * (3 * 512 * 64);
#pragma unroll
        for (int t = 0; t < 3; ++t)
            load_lds_16B(gW + (size_t)t * (512 * 64),
                         base + t * 4096 + wid * 1024);
    };

    f32x4 fa[2][4];
    auto issueA = [&](int ktn, int p) {
        const float* g = ((ktn < 16) ? pAx : pAh) + ktn * 32;
        asm volatile(
            "global_load_dwordx4 %0, %4, off\n\t"
            "global_load_dwordx4 %1, %4, off offset:16\n\t"
            "global_load_dwordx4 %2, %4, off offset:32\n\t"
            "global_load_dwordx4 %3, %4, off offset:48"
            : "=&v"(fa[p][0]), "=&v"(fa[p][1]), "=&v"(fa[p][2]), "=&v"(fa[p][3])
            : "v"(g)
            : "memory");
    };

    auto cvt2 = [](float lo, float hi) {
        unsigned int r;
        asm("v_cvt_pk_bf16_f32 %0, %1, %2" : "=v"(r) : "v"(lo), "v"(hi));
        return r;
    };

    // convert fa[p] -> A slot `slot` (data guaranteed landed by caller's vmcnt)
    auto convertA = [&](int p, int slot) {
        __builtin_amdgcn_sched_barrier(0);   // rule 18: cvt must not hoist above vmcnt
        uint4v q0, q1;
        q0.x = cvt2(fa[p][0][0], fa[p][0][1]); q0.y = cvt2(fa[p][0][2], fa[p][0][3]);
        q0.z = cvt2(fa[p][1][0], fa[p][1][1]); q0.w = cvt2(fa[p][1][2], fa[p][1][3]);
        q1.x = cvt2(fa[p][2][0], fa[p][2][1]); q1.y = cvt2(fa[p][2][2], fa[p][2][3]);
        q1.z = cvt2(fa[p][3][0], fa[p][3][1]); q1.w = cvt2(fa[p][3][2], fa[p][3][3]);
        char* base = smem + slot * ASLOT;
        *(uint4v*)(base + dsA0) = q0;
        *(uint4v*)(base + dsA1) = q1;
    };

    // prologue: W(0..2); A(0) converted to slot0; A(1) in flight in fa[1]
    stageW(0, 0);
    stageW(1, 1);
    stageW(2, 2);
    issueA(0, 0);
    asm volatile("s_waitcnt vmcnt(0)" ::: "memory");
    convertA(0, 0);
    issueA(1, 1);

    // body kt: wait -> barrier -> issueA(kt+2) -> stageW(kt+3) -> ds_reads
    //          -> convert A(kt+1) -> MFMAs.  All buf/slot/parity args literal.
    auto body = [&](int kt, int bufW, int slotA, int wait, f32x4(&accC)[4][2]) {
        if (wait == 3) asm volatile("s_waitcnt vmcnt(3) lgkmcnt(0)" ::: "memory");
        else           asm volatile("s_waitcnt vmcnt(0) lgkmcnt(0)" ::: "memory");
        __builtin_amdgcn_s_barrier();
        const int p = slotA;               // = kt&1
        if (kt + 2 < NKT) issueA(kt + 2, p);
        if (kt + 3 < NKT) stageW((kt + 3) & 3, kt + 3);
        const char* aS = smem + slotA * ASLOT;
        const char* wB = smem + bufW * WBUFB;   // + WBASE via wBase
        bf16x8 a[4], bb[3][2];
#pragma unroll
        for (int mi = 0; mi < 4; ++mi)
            a[mi] = __builtin_bit_cast(bf16x8,
                *(const uint4v*)(aS + aBase + mi * 1024));
#pragma unroll
        for (int t = 0; t < 3; ++t)
#pragma unroll
            for (int ni = 0; ni < 2; ++ni)
                bb[t][ni] = __builtin_bit_cast(bf16x8,
                    *(const uint4v*)(wB + wBase + t * 4096 + ni * 1024));
        if (kt + 1 < NKT) convertA(p ^ 1, slotA ^ 1);   // zero-wait: loaded last body
        __builtin_amdgcn_s_setprio(1);
#pragma unroll
        for (int ni = 0; ni < 2; ++ni) {
#pragma unroll
            for (int mi = 0; mi < 4; ++mi)
                accU[mi][ni] = __builtin_amdgcn_mfma_f32_16x16x32_bf16(
                    a[mi], bb[0][ni], accU[mi][ni], 0, 0, 0);
#pragma unroll
            for (int mi = 0; mi < 4; ++mi)
                accR[mi][ni] = __builtin_amdgcn_mfma_f32_16x16x32_bf16(
                    a[mi], bb[1][ni], accR[mi][ni], 0, 0, 0);
#pragma unroll
            for (int mi = 0; mi < 4; ++mi)
                accC[mi][ni] = __builtin_amdgcn_mfma_f32_16x16x32_bf16(
                    a[mi], bb[2][ni], accC[mi][ni], 0, 0, 0);
        }
        __builtin_amdgcn_s_setprio(0);
    };

    // kt 0..15: x-half -> cx.  waits: kt0 = 0, else 3 (tail handled below)
    body(0, 0, 0, 0, accCx);
    body(1, 1, 1, 3, accCx);
    body(2, 2, 0, 3, accCx);
    body(3, 3, 1, 3, accCx);
    for (int g = 1; g < 4; ++g) {
        const int k0 = g * 4;
        body(k0 + 0, 0, 0, 3, accCx);
        body(k0 + 1, 1, 1, 3, accCx);
        body(k0 + 2, 2, 0, 3, accCx);
        body(k0 + 3, 3, 1, 3, accCx);
    }
    // kt 16..31: h-half -> ch
    for (int g = 4; g < 7; ++g) {
        const int k0 = g * 4;
        body(k0 + 0, 0, 0, 3, accCh);
        body(k0 + 1, 1, 1, 3, accCh);
        body(k0 + 2, 2, 0, 3, accCh);
        body(k0 + 3, 3, 1, 3, accCh);
    }
    body(28, 0, 0, 3, accCh);
    body(29, 1, 1, 3, accCh);
    body(30, 2, 0, 0, accCh);   // converts A(31): must drain (no newer W issued)
    body(31, 3, 1, 0, accCh);

    // ---- fused epilogue ----
#pragma unroll
    for (int ni = 0; ni < 2; ++ni) {
        const int col = nb * 64 + wn * 32 + ni * 16 + cl;
        const float bU = bu[col];
        const float bR = br[col];
        const float bC = bc[col];
#pragma unroll
        for (int mi = 0; mi < 4; ++mi) {
#pragma unroll
            for (int j = 0; j < 4; ++j) {
                const int row = mb * 128 + wm * 64 + mi * 16 + kg * 4 + j;
                const float up = accU[mi][ni][j] + bU;
                const float rp = accR[mi][ni][j] + bR;
                const float u = 1.f / (1.f + __expf(-up));
                const float r = 1.f / (1.f + __expf(-rp));
                const float cpre = accCx[mi][ni][j] + bC + r * accCh[mi][ni][j];
                const float e = __expf(-2.f * cpre);
                const float cc = (1.f - e) / (1.f + e);   // tanh
                const float aa = att[row];
                const float hv = h[(size_t)row * 512 + col];
                const float u_ = aa * u;
                out[(size_t)row * 512 + col] = (1.f - u_) * hv + u_ * cc;
            }
        }
    }
}

extern "C" void kernel_launch(void* const* d_in, const int* in_sizes, int n_in,
                              void* d_out, int out_size, void* d_ws, size_t ws_size,
                              hipStream_t stream) {
    const float* x    = (const float*)d_in[0];
    const float* h    = (const float*)d_in[1];
    const float* att  = (const float*)d_in[2];
    const float* Wu_x = (const float*)d_in[3];
    const float* bu   = (const float*)d_in[4];
    const float* Wu_h = (const float*)d_in[5];
    const float* Wr_x = (const float*)d_in[6];
    const float* br   = (const float*)d_in[7];
    const float* Wr_h = (const float*)d_in[8];
    const float* Wc_x = (const float*)d_in[9];
    const float* bc   = (const float*)d_in[10];
    const float* Wc_h = (const float*)d_in[11];
    unsigned short* Wt2 = (unsigned short*)d_ws;   // 3 MB
    float* out = (float*)d_out;

    prep_weights<<<dim3(32, 16, 3), 256, 0, stream>>>(Wu_x, Wu_h, Wr_x, Wr_h, Wc_x, Wc_h, Wt2);

    hipFuncSetAttribute((const void*)augru_main,
                        hipFuncAttributeMaxDynamicSharedMemorySize, LDS_TOTAL);
    augru_main<<<dim3(2048), THREADS, LDS_TOTAL, stream>>>(
        x, h, att, Wt2, bu, br, bc, out);
}